// Round 1
// baseline (1250.802 us; speedup 1.0000x reference)
//
#include <hip/hip_runtime.h>

#define BB 8
#define SS 2048
#define DDIM 128
#define TM 16              // q rows per block (4 per wave)
#define KT 128             // k-tile rows staged in LDS
#define NT (SS / KT)       // 16 tiles
#define NPK (SS / 64)      // 32 scores per lane per row

// ---------------- V transpose: V[b][k][d] -> Vt[b][d][k] ----------------
__global__ __launch_bounds__(256)
void vtranspose(const float* __restrict__ V, float* __restrict__ Vt) {
  __shared__ float t[32][33];
  const int b  = blockIdx.z;
  const int d0 = blockIdx.x * 32;
  const int k0 = blockIdx.y * 32;
  const float* Vb  = V  + (size_t)b * SS * DDIM;
  float*       Vtb = Vt + (size_t)b * DDIM * SS;
  const int lx = threadIdx.x & 31;
  const int ly = threadIdx.x >> 5;   // 0..7
#pragma unroll
  for (int i = 0; i < 32; i += 8)
    t[ly + i][lx] = Vb[(size_t)(k0 + ly + i) * DDIM + d0 + lx];
  __syncthreads();
#pragma unroll
  for (int i = 0; i < 32; i += 8)
    Vtb[(size_t)(d0 + ly + i) * SS + k0 + lx] = t[lx][ly + i];
}

// ---------------- fused entmax attention ----------------
__global__ __launch_bounds__(256, 2)
void attn_fused(const float* __restrict__ Q, const float* __restrict__ K,
                const float* __restrict__ Vt, float* __restrict__ Out) {
  __shared__ float lds[KT * DDIM];   // 64 KiB; reused as V slice in phase 4

  const int tid  = threadIdx.x;
  const int lane = tid & 63;
  const int wid  = __builtin_amdgcn_readfirstlane(tid >> 6);  // uniform wave id
  const int b    = blockIdx.x & 7;        // batch -> XCD pinning
  const int qt   = blockIdx.x >> 3;       // 0..127

  const float* Qw  = Q  + (size_t)(b * SS + qt * TM + wid * 4) * DDIM;  // uniform
  const float* Kb  = K  + (size_t)b * SS * DDIM;
  const float* Vtb = Vt + (size_t)b * DDIM * SS;
  float*       Ow  = Out + (size_t)(b * SS + qt * TM + wid * 4) * DDIM;

  // scores: 4 q-rows x 32 k per lane.  k(p) = 64*p + lane
  float sc[4][NPK];
#pragma unroll
  for (int r = 0; r < 4; ++r)
#pragma unroll
    for (int p = 0; p < NPK; ++p) sc[r][p] = 0.f;

  const int swz = lane & 31;

  // ---------- phase 1: scores = Q K^T ----------
#pragma unroll
  for (int t = 0; t < NT; ++t) {
    __syncthreads();
    {
      const float4* src = (const float4*)(Kb + (size_t)t * KT * DDIM);
      const int c4   = tid & 31;
      const int row0 = tid >> 5;
#pragma unroll
      for (int i = 0; i < 16; ++i) {
        const int row = row0 + i * 8;
        float4 v = src[row * 32 + c4];
        *(float4*)&lds[row * DDIM + (((c4 ^ (row & 31))) << 2)] = v;
      }
    }
    __syncthreads();
    for (int c = 0; c < 32; ++c) {   // rolled loop: d-chunk of 4
      const int sw = (c ^ swz) << 2;
      const float4 k0 = *(const float4*)&lds[lane * DDIM + sw];
      const float4 k1 = *(const float4*)&lds[(lane + 64) * DDIM + sw];
#pragma unroll
      for (int r = 0; r < 4; ++r) {
        const float q0 = Qw[r * DDIM + c * 4 + 0];
        const float q1 = Qw[r * DDIM + c * 4 + 1];
        const float q2 = Qw[r * DDIM + c * 4 + 2];
        const float q3 = Qw[r * DDIM + c * 4 + 3];
        sc[r][2 * t + 0] = fmaf(q0, k0.x, sc[r][2 * t + 0]);
        sc[r][2 * t + 0] = fmaf(q1, k0.y, sc[r][2 * t + 0]);
        sc[r][2 * t + 0] = fmaf(q2, k0.z, sc[r][2 * t + 0]);
        sc[r][2 * t + 0] = fmaf(q3, k0.w, sc[r][2 * t + 0]);
        sc[r][2 * t + 1] = fmaf(q0, k1.x, sc[r][2 * t + 1]);
        sc[r][2 * t + 1] = fmaf(q1, k1.y, sc[r][2 * t + 1]);
        sc[r][2 * t + 1] = fmaf(q2, k1.z, sc[r][2 * t + 1]);
        sc[r][2 * t + 1] = fmaf(q3, k1.w, sc[r][2 * t + 1]);
      }
    }
  }

  // ---------- phase 2: z = 0.5*s, row max, bisection ----------
  float tmin[4], tmax[4], tau[4], Z[4];
#pragma unroll
  for (int r = 0; r < 4; ++r) {
#pragma unroll
    for (int p = 0; p < NPK; ++p) sc[r][p] *= 0.5f;   // (alpha-1)*scores
    float m = sc[r][0];
#pragma unroll
    for (int p = 1; p < NPK; ++p) m = fmaxf(m, sc[r][p]);
#pragma unroll
    for (int s = 1; s <= 32; s <<= 1) m = fmaxf(m, __shfl_xor(m, s));
    tmin[r] = m - 1.0f;
    tmax[r] = m - 0.022097086912079608f;   // S^(1-alpha) = 2048^-0.5
    tau[r]  = 0.5f * (tmin[r] + tmax[r]);
    Z[r]    = 0.f;
  }

  for (int it = 0; it < 100; ++it) {
    bool changed = false;
#pragma unroll
    for (int r = 0; r < 4; ++r) {
      const float tr = 0.5f * (tmin[r] + tmax[r]);
      tau[r] = tr;
      float zp = 0.f;
#pragma unroll
      for (int p = 0; p < NPK; ++p) {
        const float tt = fmaxf(sc[r][p] - tr, 0.f);
        zp = fmaf(tt, tt, zp);
      }
#pragma unroll
      for (int s = 1; s <= 32; s <<= 1) zp += __shfl_xor(zp, s);
      Z[r] = zp;
      const float nmin = (zp >= 1.f) ? tr : tmin[r];
      const float nmax = (zp >= 1.f) ? tmax[r] : tr;
      changed = changed || (nmin != tmin[r]) || (nmax != tmax[r]);
      tmin[r] = nmin;
      tmax[r] = nmax;
    }
    if (!changed) break;   // fixed point: identical to running all 100 iters
  }

  // ---------- phase 3: weights = max(z-tau,0)^2 / Z ----------
#pragma unroll
  for (int r = 0; r < 4; ++r) {
    const float invZ = 1.0f / Z[r];
#pragma unroll
    for (int p = 0; p < NPK; ++p) {
      const float tt = fmaxf(sc[r][p] - tau[r], 0.f);
      sc[r][p] = tt * tt * invZ;
    }
  }

  // ---------- phase 4: out = weights @ V ----------
  for (int c = 0; c < 32; ++c) {       // d-chunk of 4
    __syncthreads();
#pragma unroll
    for (int s = 0; s < 8; ++s) {      // stage V slice [2048][4] = 32 KiB
      const int k = s * 256 + tid;
      float4 v;
      v.x = Vtb[(size_t)(c * 4 + 0) * SS + k];
      v.y = Vtb[(size_t)(c * 4 + 1) * SS + k];
      v.z = Vtb[(size_t)(c * 4 + 2) * SS + k];
      v.w = Vtb[(size_t)(c * 4 + 3) * SS + k];
      *(float4*)&lds[k * 4] = v;
    }
    __syncthreads();
    float acc[4][4];
#pragma unroll
    for (int r = 0; r < 4; ++r)
#pragma unroll
      for (int j = 0; j < 4; ++j) acc[r][j] = 0.f;
#pragma unroll
    for (int p = 0; p < NPK; ++p) {
      const float4 v = *(const float4*)&lds[(p * 64 + lane) * 4];
#pragma unroll
      for (int r = 0; r < 4; ++r) {
        acc[r][0] = fmaf(sc[r][p], v.x, acc[r][0]);
        acc[r][1] = fmaf(sc[r][p], v.y, acc[r][1]);
        acc[r][2] = fmaf(sc[r][p], v.z, acc[r][2]);
        acc[r][3] = fmaf(sc[r][p], v.w, acc[r][3]);
      }
    }
#pragma unroll
    for (int s = 1; s <= 32; s <<= 1)
#pragma unroll
      for (int r = 0; r < 4; ++r)
#pragma unroll
        for (int j = 0; j < 4; ++j)
          acc[r][j] += __shfl_xor(acc[r][j], s);
    if (lane < 16) {
      const int r = lane >> 2, j = lane & 3;
      float v = acc[0][0];
#pragma unroll
      for (int rr = 0; rr < 4; ++rr)
#pragma unroll
        for (int jj = 0; jj < 4; ++jj)
          if (r == rr && j == jj) v = acc[rr][jj];
      Ow[r * DDIM + c * 4 + j] = v;
    }
  }
}

extern "C" void kernel_launch(void* const* d_in, const int* in_sizes, int n_in,
                              void* d_out, int out_size, void* d_ws, size_t ws_size,
                              hipStream_t stream) {
  const float* Q = (const float*)d_in[0];
  const float* K = (const float*)d_in[1];
  const float* V = (const float*)d_in[2];
  float* out = (float*)d_out;
  float* Vt  = (float*)d_ws;   // 8 MiB: Vt[b][d][k]

  dim3 tg(DDIM / 32, SS / 32, BB);          // 4 x 64 x 8
  hipLaunchKernelGGL(vtranspose, tg, dim3(256), 0, stream, V, Vt);

  const int grid = BB * (SS / TM);          // 1024 blocks
  hipLaunchKernelGGL(attn_fused, dim3(grid), dim3(256), 0, stream, Q, K, Vt, out);
}

// Round 2
// 1028.206 us; speedup vs baseline: 1.2165x; 1.2165x over previous
//
#include <hip/hip_runtime.h>

#define BB 8
#define SS 2048
#define DDIM 128
#define TM 8               // q rows per block (2 per wave)
#define KT 64              // k-tile rows staged in LDS (32 KiB)
#define NT (SS / KT)       // 32 tiles
#define NPK (SS / 64)      // 32 scores per lane per row

// ---------------- V transpose: V[b][k][d] -> Vt[b][d][k] ----------------
__global__ __launch_bounds__(256)
void vtranspose(const float* __restrict__ V, float* __restrict__ Vt) {
  __shared__ float t[32][33];
  const int b  = blockIdx.z;
  const int d0 = blockIdx.x * 32;
  const int k0 = blockIdx.y * 32;
  const float* Vb  = V  + (size_t)b * SS * DDIM;
  float*       Vtb = Vt + (size_t)b * DDIM * SS;
  const int lx = threadIdx.x & 31;
  const int ly = threadIdx.x >> 5;   // 0..7
#pragma unroll
  for (int i = 0; i < 32; i += 8)
    t[ly + i][lx] = Vb[(size_t)(k0 + ly + i) * DDIM + d0 + lx];
  __syncthreads();
#pragma unroll
  for (int i = 0; i < 32; i += 8)
    Vtb[(size_t)(d0 + ly + i) * SS + k0 + lx] = t[lx][ly + i];
}

// ---------------- fused entmax attention ----------------
// Wave owns 2 q-rows x all 2048 k. Lane holds k = 64*p + lane, p in [0,32).
// sc[2][32] = 64 VGPRs -> no spill (R1 spilled with 128).
__global__ __launch_bounds__(256, 2)
void attn_fused(const float* __restrict__ Q, const float* __restrict__ K,
                const float* __restrict__ Vt, float* __restrict__ Out) {
  __shared__ float lds[KT * DDIM];   // 32 KiB; reused as V slice in phase 4

  const int tid  = threadIdx.x;
  const int lane = tid & 63;
  const int wid  = __builtin_amdgcn_readfirstlane(tid >> 6);  // uniform wave id
  const int b    = blockIdx.x & 7;        // batch -> XCD pinning (round-robin)
  const int qt   = blockIdx.x >> 3;       // 0..255

  const float* Qw  = Q  + (size_t)(b * SS + qt * TM + wid * 2) * DDIM;  // uniform
  const float* Kb  = K  + (size_t)b * SS * DDIM;
  const float* Vtb = Vt + (size_t)b * DDIM * SS;
  float*       Ow  = Out + (size_t)(b * SS + qt * TM + wid * 2) * DDIM;

  float sc[2][NPK];
#pragma unroll
  for (int r = 0; r < 2; ++r)
#pragma unroll
    for (int p = 0; p < NPK; ++p) sc[r][p] = 0.f;

  const int swz = lane & 31;

  // ---------- phase 1: scores = Q K^T ----------
#pragma unroll
  for (int t = 0; t < NT; ++t) {
    __syncthreads();
    {
      const float4* src = (const float4*)(Kb + (size_t)t * KT * DDIM);
      const int c4   = tid & 31;
      const int row0 = tid >> 5;
#pragma unroll
      for (int i = 0; i < 8; ++i) {        // 64 rows x 128 d = 32 KiB
        const int row = row0 + i * 8;
        float4 v = src[row * 32 + c4];
        *(float4*)&lds[row * DDIM + ((c4 ^ (row & 31)) << 2)] = v;
      }
    }
    __syncthreads();
    for (int c = 0; c < 32; ++c) {   // rolled: d-chunk of 4
      const int sw = (c ^ swz) << 2;
      const float4 k0 = *(const float4*)&lds[lane * DDIM + sw];  // row = lane (0 conflicts, R1-measured)
#pragma unroll
      for (int r = 0; r < 2; ++r) {
        const float q0 = Qw[r * DDIM + c * 4 + 0];
        const float q1 = Qw[r * DDIM + c * 4 + 1];
        const float q2 = Qw[r * DDIM + c * 4 + 2];
        const float q3 = Qw[r * DDIM + c * 4 + 3];
        sc[r][t] = fmaf(q0, k0.x, sc[r][t]);
        sc[r][t] = fmaf(q1, k0.y, sc[r][t]);
        sc[r][t] = fmaf(q2, k0.z, sc[r][t]);
        sc[r][t] = fmaf(q3, k0.w, sc[r][t]);
      }
    }
  }

  // ---------- phase 2: z = 0.5*s, row max, bisection ----------
  float tmin[2], tmax[2], tau[2], Z[2];
#pragma unroll
  for (int r = 0; r < 2; ++r) {
#pragma unroll
    for (int p = 0; p < NPK; ++p) sc[r][p] *= 0.5f;   // (alpha-1)*scores
    float m = sc[r][0];
#pragma unroll
    for (int p = 1; p < NPK; ++p) m = fmaxf(m, sc[r][p]);
#pragma unroll
    for (int s = 1; s <= 32; s <<= 1) m = fmaxf(m, __shfl_xor(m, s));
    tmin[r] = m - 1.0f;
    tmax[r] = m - 0.022097086912079608f;   // S^(1-alpha) = 2048^-0.5
    tau[r]  = 0.5f * (tmin[r] + tmax[r]);
    Z[r]    = 0.f;
  }

  for (int it = 0; it < 100; ++it) {
    bool changed = false;
#pragma unroll
    for (int r = 0; r < 2; ++r) {
      const float tr = 0.5f * (tmin[r] + tmax[r]);
      tau[r] = tr;
      float zp = 0.f;
#pragma unroll
      for (int p = 0; p < NPK; ++p) {
        const float tt = fmaxf(sc[r][p] - tr, 0.f);
        zp = fmaf(tt, tt, zp);
      }
#pragma unroll
      for (int s = 1; s <= 32; s <<= 1) zp += __shfl_xor(zp, s);
      Z[r] = zp;
      const float nmin = (zp >= 1.f) ? tr : tmin[r];
      const float nmax = (zp >= 1.f) ? tmax[r] : tr;
      changed = changed || (nmin != tmin[r]) || (nmax != tmax[r]);
      tmin[r] = nmin;
      tmax[r] = nmax;
    }
    if (!changed) break;   // fixed point: bit-identical to running all 100 iters
  }

  // ---------- phase 3: weights = max(z-tau,0)^2 / Z ----------
#pragma unroll
  for (int r = 0; r < 2; ++r) {
    const float invZ = 1.0f / Z[r];
#pragma unroll
    for (int p = 0; p < NPK; ++p) {
      const float tt = fmaxf(sc[r][p] - tau[r], 0.f);
      sc[r][p] = tt * tt * invZ;
    }
  }

  // ---------- phase 4: out = weights @ V ----------
  for (int c = 0; c < 32; ++c) {       // d-chunk of 4
    __syncthreads();
#pragma unroll
    for (int s = 0; s < 8; ++s) {      // stage V slice [2048][4] = 32 KiB
      const int k = s * 256 + tid;
      float4 v;
      v.x = Vtb[(size_t)(c * 4 + 0) * SS + k];
      v.y = Vtb[(size_t)(c * 4 + 1) * SS + k];
      v.z = Vtb[(size_t)(c * 4 + 2) * SS + k];
      v.w = Vtb[(size_t)(c * 4 + 3) * SS + k];
      *(float4*)&lds[k * 4] = v;
    }
    __syncthreads();
    float acc[2][4];
#pragma unroll
    for (int r = 0; r < 2; ++r)
#pragma unroll
      for (int j = 0; j < 4; ++j) acc[r][j] = 0.f;
#pragma unroll
    for (int p = 0; p < NPK; ++p) {
      const float4 v = *(const float4*)&lds[(p * 64 + lane) * 4];
#pragma unroll
      for (int r = 0; r < 2; ++r) {
        acc[r][0] = fmaf(sc[r][p], v.x, acc[r][0]);
        acc[r][1] = fmaf(sc[r][p], v.y, acc[r][1]);
        acc[r][2] = fmaf(sc[r][p], v.z, acc[r][2]);
        acc[r][3] = fmaf(sc[r][p], v.w, acc[r][3]);
      }
    }
#pragma unroll
    for (int s = 1; s <= 32; s <<= 1)
#pragma unroll
      for (int r = 0; r < 2; ++r)
#pragma unroll
        for (int j = 0; j < 4; ++j)
          acc[r][j] += __shfl_xor(acc[r][j], s);
    if (lane < 8) {
      const int r = lane >> 2, j = lane & 3;
      float v = acc[0][0];
#pragma unroll
      for (int rr = 0; rr < 2; ++rr)
#pragma unroll
        for (int jj = 0; jj < 4; ++jj)
          if (r == rr && j == jj) v = acc[rr][jj];
      Ow[r * DDIM + c * 4 + j] = v;
    }
  }
}

extern "C" void kernel_launch(void* const* d_in, const int* in_sizes, int n_in,
                              void* d_out, int out_size, void* d_ws, size_t ws_size,
                              hipStream_t stream) {
  const float* Q = (const float*)d_in[0];
  const float* K = (const float*)d_in[1];
  const float* V = (const float*)d_in[2];
  float* out = (float*)d_out;
  float* Vt  = (float*)d_ws;   // 8 MiB: Vt[b][d][k]

  dim3 tg(DDIM / 32, SS / 32, BB);          // 4 x 64 x 8
  hipLaunchKernelGGL(vtranspose, tg, dim3(256), 0, stream, V, Vt);

  const int grid = BB * (SS / TM);          // 2048 blocks
  hipLaunchKernelGGL(attn_fused, dim3(grid), dim3(256), 0, stream, Q, K, Vt, out);
}